// Round 15
// baseline (335.642 us; speedup 1.0000x reference)
//
#include <hip/hip_runtime.h>
#include <hip/hip_bf16.h>

#define NN    20000   // nodes
#define KE    16      // ego-net size
#define FIN   128     // input feats / hidden
#define FOUT2 64      // output classes
#define NE    640000  // edges
#define RK    8       // counter replicas (kills same-address atomic serialization)
#define KEYS  (NN * RK)             // 160000 expanded keys per array
#define SB    157                   // scan blocks per array: ceil(KEYS/1024)
#define TOT   (NE + NN * KE)        // 960000 items in unified hist/bucket space
#define HB    469                   // hist blocks: ceil(TOT/8/256)
#define GB1   1250                  // dense-GEMM blocks (16 rows each)
#define APAD  17                    // padded row stride for A in LDS

// ---- bf16 helpers (ushort storage, fp32 math) ----
__device__ __forceinline__ float bf2f(unsigned short u) {
    union { float f; unsigned int i; } c; c.i = ((unsigned int)u) << 16; return c.f;
}
__device__ __forceinline__ unsigned short f2bf(float f) {
    union { float f; unsigned int i; } c; c.f = f;
    unsigned int lsb = (c.i >> 16) & 1u;
    c.i += 0x7fffu + lsb;           // round-to-nearest-even
    return (unsigned short)(c.i >> 16);
}
__device__ __forceinline__ float4 ldx4(const unsigned short* p, size_t i) {
    ushort4 u = *(const ushort4*)(p + i);
    float4 r; r.x = bf2f(u.x); r.y = bf2f(u.y); r.z = bf2f(u.z); r.w = bf2f(u.w);
    return r;
}
__device__ __forceinline__ float2 ldu2(const unsigned short* p, size_t i) {
    ushort2 u = *(const ushort2*)(p + i);
    float2 r; r.x = bf2f(u.x); r.y = bf2f(u.y); return r;
}

// ---- mega: hist+pos [0,HB) || xW1 = x @ W_ego1 [HB,HB+GB1) || W_combo ------
__global__ __launch_bounds__(256) void mega_kernel(
    const int* __restrict__ dst, const int* __restrict__ ego_flat,
    int* __restrict__ deg, int* __restrict__ edeg, int* __restrict__ posarr,
    const float* __restrict__ x, const float* __restrict__ W1,
    unsigned short* __restrict__ xW1,
    const float* __restrict__ We2, const float* __restrict__ Wg2,
    const float* __restrict__ be2, float* __restrict__ Wc, float* __restrict__ bc) {
    __shared__ float rl[16][FIN];
    const int t = threadIdx.x;
    if (blockIdx.x < HB) {          // ---- histogram + rank, replicated keys ----
        const int base = blockIdx.x * 2048 + t;
#pragma unroll
        for (int q = 0; q < 8; ++q) {
            const int i = base + q * 256;
            if (i < TOT) {
                if (i < NE) posarr[i] = atomicAdd(&deg[dst[i] * RK + (i & 7)], 1);
                else        posarr[i] = atomicAdd(&edeg[ego_flat[i - NE] * RK + (i & 7)], 1);
            }
        }
        return;
    }
    if (blockIdx.x < HB + GB1) {    // ---- dense GEMM: xW1 = x @ W1 -> bf16 ----
        const int r0 = (blockIdx.x - HB) * 16;
        for (int idx = t; idx < 16 * FIN; idx += 256)
            rl[idx >> 7][idx & 127] = x[(size_t)(r0 + (idx >> 7)) * FIN + (idx & 127)];
        __syncthreads();
        const int j = t & 127, g = t >> 7;
        float acc[8] = {};
        for (int k = 0; k < FIN; k += 4) {
            const float w0 = W1[k * FIN + j],       w1 = W1[(k + 1) * FIN + j];
            const float w2 = W1[(k + 2) * FIN + j], w3 = W1[(k + 3) * FIN + j];
#pragma unroll
            for (int r = 0; r < 8; ++r) {
                float4 rv = *(const float4*)&rl[g * 8 + r][k];
                acc[r] += rv.x * w0 + rv.y * w1 + rv.z * w2 + rv.w * w3;
            }
        }
#pragma unroll
        for (int r = 0; r < 8; ++r)
            xW1[(size_t)(r0 + g * 8 + r) * FIN + j] = f2bf(acc[r]);
        return;
    }
    // ---- W_combo = W_ego2 @ W_gcn2 (128x64), b_combo = b_ego2 @ W_gcn2 ----
    const int wb = blockIdx.x - HB - GB1;
    if (wb < 32) {
        const int row = wb * 4 + (t >> 6);
        const int j = t & 63;
        float s = 0.f;
        for (int k = 0; k < FIN; ++k) s += We2[row * FIN + k] * Wg2[k * FOUT2 + j];
        Wc[row * FOUT2 + j] = s;
    } else if (t < FOUT2) {
        float s = 0.f;
        for (int k = 0; k < FIN; ++k) s += be2[k] * Wg2[k * FOUT2 + t];
        bc[t] = s;
    }
}

// ---- scan p1: 1024 entries/block (4/thread) over deg then edeg -------------
__global__ __launch_bounds__(256) void scan_p1_kernel(
    const int* __restrict__ deg, const int* __restrict__ edeg,
    int* __restrict__ scantmp, int* __restrict__ bsums) {
    const int arr = (blockIdx.x >= SB) ? 1 : 0;
    const int blk = blockIdx.x - arr * SB;
    const int t = threadIdx.x;
    const int base = blk * 1024 + t * 4;
    const int* cnt = arr ? edeg : deg;
    int4 v = *(const int4*)&cnt[base];   // OOB-safe: reads stay inside ws
    if (base + 0 >= KEYS) v.x = 0;
    if (base + 1 >= KEYS) v.y = 0;
    if (base + 2 >= KEYS) v.z = 0;
    if (base + 3 >= KEYS) v.w = 0;
    const int s = v.x + v.y + v.z + v.w;
    __shared__ int sh[256];
    sh[t] = s;
    __syncthreads();
    for (int o = 1; o < 256; o <<= 1) {
        int u = (t >= o) ? sh[t - o] : 0;
        __syncthreads();
        sh[t] += u;
        __syncthreads();
    }
    const int p = sh[t] - s;  // exclusive prefix of this thread's quad
    if (base + 3 < KEYS) {
        int4 o; o.x = p; o.y = p + v.x; o.z = p + v.x + v.y; o.w = p + v.x + v.y + v.z;
        *(int4*)&scantmp[arr * KEYS + base] = o;
    } else {
        int run = p;
        if (base + 0 < KEYS) { scantmp[arr * KEYS + base + 0] = run; run += v.x; }
        if (base + 1 < KEYS) { scantmp[arr * KEYS + base + 1] = run; run += v.y; }
        if (base + 2 < KEYS) { scantmp[arr * KEYS + base + 2] = run; run += v.z; }
        if (base + 3 < KEYS) { scantmp[arr * KEYS + base + 3] = run; }
    }
    if (t == 255) bsums[arr * SB + blk] = sh[255];
}
// ---- scan p3: each block re-derives block offset from bsums in LDS ---------
__global__ __launch_bounds__(256) void scan_p3_kernel(
    const int* __restrict__ scantmp, const int* __restrict__ bsums,
    int* __restrict__ rowstart, int* __restrict__ erowstart) {
    const int arr = (blockIdx.x >= SB) ? 1 : 0;
    const int blk = blockIdx.x - arr * SB;
    const int t = threadIdx.x;
    __shared__ int sh[256];
    int v = (t < SB) ? bsums[arr * SB + t] : 0;
    sh[t] = v;
    __syncthreads();
    for (int o = 1; o < 256; o <<= 1) {
        int u = (t >= o) ? sh[t - o] : 0;
        __syncthreads();
        sh[t] += u;
        __syncthreads();
    }
    const int blkofs = (blk == 0) ? 0 : sh[blk - 1];
    const int base = blk * 1024 + t * 4;
    int* out = arr ? erowstart : rowstart;
    if (base + 3 < KEYS) {
        int4 sv = *(const int4*)&scantmp[arr * KEYS + base];
        int4 o; o.x = sv.x + blkofs; o.y = sv.y + blkofs; o.z = sv.z + blkofs; o.w = sv.w + blkofs;
        *(int4*)&out[base] = o;
    } else {
        for (int q = 0; q < 4; ++q)
            if (base + q < KEYS) out[base + q] = scantmp[arr * KEYS + base + q] + blkofs;
    }
    if (blockIdx.x == 0 && t == 0) { rowstart[KEYS] = NE; erowstart[KEYS] = NN * KE; }
}

// ---- bucket: scatter into CSR slots (no atomics) + dinv (first 79 blocks) --
__global__ void bucket2_kernel(const int* __restrict__ src, const int* __restrict__ dst,
                               const int* __restrict__ ego_flat,
                               const int* __restrict__ rowstart, const int* __restrict__ erowstart,
                               const int* __restrict__ posarr,
                               int* __restrict__ csr_src, int* __restrict__ yslot,
                               float* __restrict__ dinv) {
    const int t = threadIdx.x;
    if (blockIdx.x < 79) {           // dinv from rowstart deltas (edge counts)
        const int v = blockIdx.x * 256 + t;
        if (v < NN)
            dinv[v] = rsqrtf((float)(rowstart[(v + 1) * RK] - rowstart[v * RK] + 1));
    }
    const int base = blockIdx.x * 2048 + t;
#pragma unroll
    for (int q = 0; q < 8; ++q) {
        const int i = base + q * 256;
        if (i < TOT) {
            if (i < NE) {
                const int kk = dst[i] * RK + (i & 7);
                csr_src[rowstart[kk] + posarr[i]] = src[i];
            } else {
                const int p = i - NE;
                const int kk = ego_flat[p] * RK + (i & 7);
                yslot[p] = erowstart[kk] + posarr[i];
            }
        }
    }
}

// ---- ego apply (128-wide): Y[yslot[n,i]] = ((A@A) @ xW1[ids[n]])[i] --------
__global__ __launch_bounds__(256) void ego_apply_kernel(
    const unsigned short* __restrict__ x, const int* __restrict__ ego_ids,
    const float* __restrict__ ego_adj, const int* __restrict__ yslot,
    unsigned short* __restrict__ Y) {
    __shared__ float Ar[8][KE * APAD];
    __shared__ float As[8][256];
    __shared__ int ids[8][KE];
    __shared__ int slots[8][KE];
    const int w = threadIdx.x >> 5;
    const int c = threadIdx.x & 31;
    const int n = blockIdx.x * 8 + w;
    const float* a = ego_adj + (size_t)n * 256;
#pragma unroll
    for (int e = 0; e < 8; ++e) {
        const int idx = c * 8 + e;
        Ar[w][(idx >> 4) * APAD + (idx & 15)] = a[idx];
    }
    if (c < KE) {
        ids[w][c] = ego_ids[n * KE + c];
        slots[w][c] = yslot[n * KE + c];
    }
    __syncthreads();
    {
        const int i = c >> 1;
        const int k0 = (c & 1) * 8;
        float s[8] = {};
#pragma unroll
        for (int j = 0; j < KE; ++j) {
            const float aij = Ar[w][i * APAD + j];
            const float* arow = &Ar[w][j * APAD + k0];
#pragma unroll
            for (int q = 0; q < 8; ++q) s[q] += aij * arow[q];
        }
        float4 s0 = {s[0], s[1], s[2], s[3]}, s1 = {s[4], s[5], s[6], s[7]};
        *(float4*)&As[w][i * 16 + k0]     = s0;
        *(float4*)&As[w][i * 16 + k0 + 4] = s1;
    }
    __syncthreads();
    float4 xg[KE];
#pragma unroll
    for (int k = 0; k < KE; ++k) xg[k] = ldx4(x, (size_t)ids[w][k] * FIN + 4 * c);
#pragma unroll
    for (int i = 0; i < KE; ++i) {
        float4 acc = {0.f, 0.f, 0.f, 0.f};
#pragma unroll
        for (int k = 0; k < KE; ++k) {
            const float a2 = As[w][i * 16 + k];
            acc.x += a2 * xg[k].x; acc.y += a2 * xg[k].y;
            acc.z += a2 * xg[k].z; acc.w += a2 * xg[k].w;
        }
        ushort4 o; o.x = f2bf(acc.x); o.y = f2bf(acc.y);
        o.z = f2bf(acc.z); o.w = f2bf(acc.w);
        *(ushort4*)(Y + (size_t)slots[w][i] * FIN + 4 * c) = o;
    }
}

// ---- dual1: rows = relu(ndeg*sumY + b1); msg = (rows @ Wg1)*dinv -> bf16 ----
__global__ __launch_bounds__(256) void dual1_kernel(
    const unsigned short* __restrict__ Y, const int* __restrict__ erowstart,
    const float* __restrict__ ndeg, const float* __restrict__ b1,
    const float* __restrict__ Wg1, const float* __restrict__ dinv,
    unsigned short* __restrict__ msg) {
    constexpr int ROWS = 8;
    const int r0 = blockIdx.x * ROWS;
    const int t = threadIdx.x;
    __shared__ float rows[ROWS][FIN];
    {
        const int wv = t >> 6;
        const int h  = (t >> 5) & 1;
        const int c  = t & 31;
        for (int rr = 0; rr < ROWS; rr += 4) {
            const int r = rr + wv;
            const int v = r0 + r;
            float4 acc = {0.f, 0.f, 0.f, 0.f};
            const int send = erowstart[(v + 1) * RK];
            int s = erowstart[v * RK] + h;
            for (; s + 2 < send; s += 4) {
                float4 a = ldx4(Y, (size_t)s * FIN + 4 * c);
                float4 d4 = ldx4(Y, (size_t)(s + 2) * FIN + 4 * c);
                acc.x += a.x + d4.x; acc.y += a.y + d4.y;
                acc.z += a.z + d4.z; acc.w += a.w + d4.w;
            }
            if (s < send) {
                float4 a = ldx4(Y, (size_t)s * FIN + 4 * c);
                acc.x += a.x; acc.y += a.y; acc.z += a.z; acc.w += a.w;
            }
            acc.x += __shfl_xor(acc.x, 32);
            acc.y += __shfl_xor(acc.y, 32);
            acc.z += __shfl_xor(acc.z, 32);
            acc.w += __shfl_xor(acc.w, 32);
            if (h == 0) {
                const float nd = ndeg[v];
                const float4 bb = *(const float4*)&b1[4 * c];
                float4 o;
                o.x = fmaxf(acc.x * nd + bb.x, 0.f);
                o.y = fmaxf(acc.y * nd + bb.y, 0.f);
                o.z = fmaxf(acc.z * nd + bb.z, 0.f);
                o.w = fmaxf(acc.w * nd + bb.w, 0.f);
                *(float4*)&rows[r][4 * c] = o;
            }
        }
    }
    __syncthreads();
    {
        const int j = t & 127;
        const int g = t >> 7;
        float acc[4] = {};
        for (int k = 0; k < FIN; k += 4) {
            const float w0 = Wg1[k * FIN + j],       w1 = Wg1[(k + 1) * FIN + j];
            const float w2 = Wg1[(k + 2) * FIN + j], w3 = Wg1[(k + 3) * FIN + j];
#pragma unroll
            for (int r = 0; r < 4; ++r) {
                float4 rv = *(const float4*)&rows[g * 4 + r][k];
                acc[r] += rv.x * w0 + rv.y * w1 + rv.z * w2 + rv.w * w3;
            }
        }
#pragma unroll
        for (int r = 0; r < 4; ++r) {
            const int v = r0 + g * 4 + r;
            msg[(size_t)v * FIN + j] = f2bf(acc[r] * dinv[v]);
        }
    }
}

// ------- GCN gather (F=128), half-split ushort4 -----------------------------
__global__ __launch_bounds__(256) void gcn_gather128_kernel(
    const unsigned short* __restrict__ msg, const int* __restrict__ rowstart,
    const int* __restrict__ csr_src, const float* __restrict__ dinv,
    const float* __restrict__ b, unsigned short* __restrict__ out) {
    const int tid = threadIdx.x;
    const int d = blockIdx.x * 4 + (tid >> 6);
    const int h = (tid >> 5) & 1;
    const int c = tid & 31;
    float4 acc = {0.f, 0.f, 0.f, 0.f};
    if (h == 0) acc = ldx4(msg, (size_t)d * FIN + 4 * c);  // self loop
    const int eend = rowstart[(d + 1) * RK];
    int e = rowstart[d * RK] + h;
    for (; e + 2 < eend; e += 4) {
        int s0 = csr_src[e], s1 = csr_src[e + 2];
        float4 a = ldx4(msg, (size_t)s0 * FIN + 4 * c);
        float4 d4 = ldx4(msg, (size_t)s1 * FIN + 4 * c);
        acc.x += a.x + d4.x; acc.y += a.y + d4.y;
        acc.z += a.z + d4.z; acc.w += a.w + d4.w;
    }
    if (e < eend) {
        float4 a = ldx4(msg, (size_t)csr_src[e] * FIN + 4 * c);
        acc.x += a.x; acc.y += a.y; acc.z += a.z; acc.w += a.w;
    }
    acc.x += __shfl_xor(acc.x, 32);
    acc.y += __shfl_xor(acc.y, 32);
    acc.z += __shfl_xor(acc.z, 32);
    acc.w += __shfl_xor(acc.w, 32);
    if (h == 0) {
        const float di = dinv[d];
        const float4 bb = *(const float4*)&b[4 * c];
        ushort4 o;
        o.x = f2bf(acc.x * di + bb.x); o.y = f2bf(acc.y * di + bb.y);
        o.z = f2bf(acc.z * di + bb.z); o.w = f2bf(acc.w * di + bb.w);
        *(ushort4*)(out + (size_t)d * FIN + 4 * c) = o;
    }
}

// ---- gemm2: hW2 = hA @ W_combo (128->64) -> bf16 ---------------------------
__global__ __launch_bounds__(256) void gemm2_kernel(
    const unsigned short* __restrict__ hA, const float* __restrict__ Wc,
    unsigned short* __restrict__ hW2) {
    __shared__ float rl[16][FIN];
    const int t = threadIdx.x;
    const int r0 = blockIdx.x * 16;
    for (int idx = t; idx < 16 * FIN; idx += 256)
        rl[idx >> 7][idx & 127] = bf2f(hA[(size_t)(r0 + (idx >> 7)) * FIN + (idx & 127)]);
    __syncthreads();
    const int j = t & 63, g = t >> 6;
    float acc[4] = {};
    for (int k = 0; k < FIN; k += 4) {
        const float w0 = Wc[k * FOUT2 + j],       w1 = Wc[(k + 1) * FOUT2 + j];
        const float w2 = Wc[(k + 2) * FOUT2 + j], w3 = Wc[(k + 3) * FOUT2 + j];
#pragma unroll
        for (int r = 0; r < 4; ++r) {
            float4 rv = *(const float4*)&rl[g * 4 + r][k];
            acc[r] += rv.x * w0 + rv.y * w1 + rv.z * w2 + rv.w * w3;
        }
    }
#pragma unroll
    for (int r = 0; r < 4; ++r)
        hW2[(size_t)(r0 + g * 4 + r) * FOUT2 + j] = f2bf(acc[r]);
}

// ---- ego apply (64-wide): Y2[yslot] = (A@A) @ hW2[ids] ---------------------
__global__ __launch_bounds__(256) void apply2_kernel(
    const unsigned short* __restrict__ hW2, const int* __restrict__ ego_ids,
    const float* __restrict__ ego_adj, const int* __restrict__ yslot,
    unsigned short* __restrict__ Y2) {
    __shared__ float Ar[8][KE * APAD];
    __shared__ float As[8][256];
    __shared__ int ids[8][KE];
    __shared__ int slots[8][KE];
    const int w = threadIdx.x >> 5;
    const int c = threadIdx.x & 31;
    const int n = blockIdx.x * 8 + w;
    const float* a = ego_adj + (size_t)n * 256;
#pragma unroll
    for (int e = 0; e < 8; ++e) {
        const int idx = c * 8 + e;
        Ar[w][(idx >> 4) * APAD + (idx & 15)] = a[idx];
    }
    if (c < KE) {
        ids[w][c] = ego_ids[n * KE + c];
        slots[w][c] = yslot[n * KE + c];
    }
    __syncthreads();
    {
        const int i = c >> 1;
        const int k0 = (c & 1) * 8;
        float s[8] = {};
#pragma unroll
        for (int j = 0; j < KE; ++j) {
            const float aij = Ar[w][i * APAD + j];
            const float* arow = &Ar[w][j * APAD + k0];
#pragma unroll
            for (int q = 0; q < 8; ++q) s[q] += aij * arow[q];
        }
        float4 s0 = {s[0], s[1], s[2], s[3]}, s1 = {s[4], s[5], s[6], s[7]};
        *(float4*)&As[w][i * 16 + k0]     = s0;
        *(float4*)&As[w][i * 16 + k0 + 4] = s1;
    }
    __syncthreads();
    float2 xg[KE];
#pragma unroll
    for (int k = 0; k < KE; ++k) xg[k] = ldu2(hW2, (size_t)ids[w][k] * FOUT2 + 2 * c);
#pragma unroll
    for (int i = 0; i < KE; ++i) {
        float sx = 0.f, sy = 0.f;
#pragma unroll
        for (int k = 0; k < KE; ++k) {
            const float a2 = As[w][i * 16 + k];
            sx += a2 * xg[k].x; sy += a2 * xg[k].y;
        }
        ushort2 o; o.x = f2bf(sx); o.y = f2bf(sy);
        *(ushort2*)(Y2 + (size_t)slots[w][i] * FOUT2 + 2 * c) = o;
    }
}

// ---- dual2 (matmul-free): m2 = ((ndeg*sumY2) + b_combo)*dinv -> bf16 -------
__global__ __launch_bounds__(256) void dual2_kernel(
    const unsigned short* __restrict__ Y2, const int* __restrict__ erowstart,
    const float* __restrict__ ndeg, const float* __restrict__ bc,
    const float* __restrict__ dinv, unsigned short* __restrict__ m2) {
    const int tid = threadIdx.x;
    const int d = blockIdx.x * 4 + (tid >> 6);
    const int h = (tid >> 5) & 1;
    const int c = tid & 31;
    float2 acc = {0.f, 0.f};
    const int send = erowstart[(d + 1) * RK];
    int s = erowstart[d * RK] + h;
    for (; s + 2 < send; s += 4) {
        float2 a = ldu2(Y2, (size_t)s * FOUT2 + 2 * c);
        float2 b2 = ldu2(Y2, (size_t)(s + 2) * FOUT2 + 2 * c);
        acc.x += a.x + b2.x; acc.y += a.y + b2.y;
    }
    if (s < send) {
        float2 a = ldu2(Y2, (size_t)s * FOUT2 + 2 * c);
        acc.x += a.x; acc.y += a.y;
    }
    acc.x += __shfl_xor(acc.x, 32);
    acc.y += __shfl_xor(acc.y, 32);
    if (h == 0) {
        const float nd = ndeg[d], di = dinv[d];
        const float2 bb = *(const float2*)&bc[2 * c];
        ushort2 o;
        o.x = f2bf((acc.x * nd + bb.x) * di);
        o.y = f2bf((acc.y * nd + bb.y) * di);
        *(ushort2*)(m2 + (size_t)d * FOUT2 + 2 * c) = o;
    }
}

// ------- fused GCN gather (F=64) + bias + log_softmax -> fp32 ---------------
__global__ __launch_bounds__(256) void gcn_gather_lsm_kernel(
    const unsigned short* __restrict__ msg, const int* __restrict__ rowstart,
    const int* __restrict__ csr_src, const float* __restrict__ dinv,
    const float* __restrict__ b, float* __restrict__ out) {
    const int tid = threadIdx.x;
    const int d = blockIdx.x * 4 + (tid >> 6);
    const int t = tid & 63;
    float s = bf2f(msg[(size_t)d * FOUT2 + t]);  // self loop
    int e = rowstart[d * RK];
    const int eend = rowstart[(d + 1) * RK];
    for (; e + 4 <= eend; e += 4) {
        int s0 = csr_src[e], s1 = csr_src[e + 1], s2 = csr_src[e + 2], s3 = csr_src[e + 3];
        s += bf2f(msg[(size_t)s0 * FOUT2 + t]) + bf2f(msg[(size_t)s1 * FOUT2 + t])
           + bf2f(msg[(size_t)s2 * FOUT2 + t]) + bf2f(msg[(size_t)s3 * FOUT2 + t]);
    }
    for (; e < eend; ++e) s += bf2f(msg[(size_t)csr_src[e] * FOUT2 + t]);
    const float xv = s * dinv[d] + b[t];
    float m = xv;
#pragma unroll
    for (int o = 32; o > 0; o >>= 1) m = fmaxf(m, __shfl_xor(m, o));
    float ex = __expf(xv - m);
    float sm = ex;
#pragma unroll
    for (int o = 32; o > 0; o >>= 1) sm += __shfl_xor(sm, o);
    out[(size_t)d * FOUT2 + t] = xv - m - __logf(sm);
}

extern "C" void kernel_launch(void* const* d_in, const int* in_sizes, int n_in,
                              void* d_out, int out_size, void* d_ws, size_t ws_size,
                              hipStream_t stream) {
    (void)in_sizes; (void)n_in; (void)out_size; (void)ws_size;
    const float* x      = (const float*)d_in[0];
    const int*   eidx   = (const int*)d_in[1];
    const int*   egoids = (const int*)d_in[2];
    const float* egoadj = (const float*)d_in[3];
    const float* ndeg   = (const float*)d_in[4];
    const float* W_ego1 = (const float*)d_in[5];
    const float* b_ego1 = (const float*)d_in[6];
    const float* W_gcn1 = (const float*)d_in[7];
    const float* b_gcn1 = (const float*)d_in[8];
    const float* W_ego2 = (const float*)d_in[9];
    const float* b_ego2 = (const float*)d_in[10];
    const float* W_gcn2 = (const float*)d_in[11];
    const float* b_gcn2 = (const float*)d_in[12];
    const int* src = eidx;
    const int* dst = eidx + NE;

    // ---- workspace layout (~115 MB) ----
    int* ip = (int*)d_ws;
    int* deg       = ip;                    // KEYS (zeroed)
    int* edeg      = deg + KEYS;            // KEYS (zeroed)
    int* rowstart  = edeg + KEYS;           // KEYS+1 (+pad to 8)
    int* erowstart = rowstart + KEYS + 8;   // KEYS+1 (+pad)
    int* csr_src   = erowstart + KEYS + 8;  // NE
    int* yslot     = csr_src + NE;          // NN*KE
    int* scantmp   = yslot + NN * KE;       // 2*KEYS
    int* bsums     = scantmp + 2 * KEYS;    // 2*SB (+pad)
    int* posarr    = bsums + 512;           // TOT
    float* dinv = (float*)(posarr + TOT);               // NN
    float* Wc   = dinv + NN;                            // 128*64 fp32
    float* bc   = Wc + FIN * FOUT2;                     // 64 (+pad)
    unsigned short* xW1 = (unsigned short*)(bc + 64);    // NN*128 bf16
    unsigned short* mA  = xW1 + (size_t)NN * FIN;        // NN*128 bf16 msgs L1
    unsigned short* hA  = mA + (size_t)NN * FIN;         // NN*128 bf16 hidden
    unsigned short* hW2 = hA + (size_t)NN * FIN;         // NN*64  bf16
    unsigned short* m2  = hW2 + (size_t)NN * FOUT2;      // NN*64  bf16 msgs L2
    unsigned short* Y   = m2 + (size_t)NN * FOUT2;       // NN*KE*128 bf16 (CSR order)

    // ---- CSR build || xW1 GEMM || W_combo ----
    (void)hipMemsetAsync(deg, 0, 2 * KEYS * sizeof(int), stream);
    mega_kernel<<<HB + GB1 + 33, 256, 0, stream>>>(dst, egoids, deg, edeg, posarr,
                                                   x, W_ego1, xW1,
                                                   W_ego2, W_gcn2, b_ego2, Wc, bc);
    scan_p1_kernel<<<2 * SB, 256, 0, stream>>>(deg, edeg, scantmp, bsums);
    scan_p3_kernel<<<2 * SB, 256, 0, stream>>>(scantmp, bsums, rowstart, erowstart);
    bucket2_kernel<<<HB, 256, 0, stream>>>(src, dst, egoids, rowstart,
                                           erowstart, posarr, csr_src, yslot, dinv);

    // ---- layer 1 ----
    ego_apply_kernel<<<NN / 8, 256, 0, stream>>>(xW1, egoids, egoadj, yslot, Y);
    dual1_kernel<<<NN / 8, 256, 0, stream>>>(Y, erowstart, ndeg, b_ego1, W_gcn1, dinv, mA);
    gcn_gather128_kernel<<<NN / 4, 256, 0, stream>>>(mA, rowstart, csr_src, dinv, b_gcn1, hA);

    // ---- layer 2 (weights pre-combined; ego runs on 64-wide hW2) ----
    gemm2_kernel<<<GB1, 256, 0, stream>>>(hA, Wc, hW2);
    apply2_kernel<<<NN / 8, 256, 0, stream>>>(hW2, egoids, egoadj, yslot, Y);
    dual2_kernel<<<NN / 4, 256, 0, stream>>>(Y, erowstart, ndeg, bc, dinv, m2);
    gcn_gather_lsm_kernel<<<NN / 4, 256, 0, stream>>>(m2, rowstart, csr_src, dinv, b_gcn2, (float*)d_out);
}

// Round 16
// 315.613 us; speedup vs baseline: 1.0635x; 1.0635x over previous
//
#include <hip/hip_runtime.h>
#include <hip/hip_bf16.h>

#define NN    20000   // nodes
#define KE    16      // ego-net size
#define FIN   128     // input feats / hidden
#define FOUT2 64      // output classes
#define NE    640000  // edges
#define NB    79      // scan blocks per array: ceil(NN/256)
#define TOT   (NE + NN * KE)        // 960000 items
#define HB    469                   // bucket blocks: ceil(TOT/8/256)
#define BE    100                   // edge-hist blocks (LDS histogram)
#define BG    50                    // ego-hist blocks
#define CE    6400                  // items per hist block (BE*CE=NE, BG*CE=NN*KE)
#define GB1   1250                  // dense-GEMM blocks (16 rows each)
#define APAD  17                    // padded row stride for A in LDS

// ---- bf16 helpers (ushort storage, fp32 math) ----
__device__ __forceinline__ float bf2f(unsigned short u) {
    union { float f; unsigned int i; } c; c.i = ((unsigned int)u) << 16; return c.f;
}
__device__ __forceinline__ unsigned short f2bf(float f) {
    union { float f; unsigned int i; } c; c.f = f;
    unsigned int lsb = (c.i >> 16) & 1u;
    c.i += 0x7fffu + lsb;           // round-to-nearest-even
    return (unsigned short)(c.i >> 16);
}
__device__ __forceinline__ float4 ldx4(const unsigned short* p, size_t i) {
    ushort4 u = *(const ushort4*)(p + i);
    float4 r; r.x = bf2f(u.x); r.y = bf2f(u.y); r.z = bf2f(u.z); r.w = bf2f(u.w);
    return r;
}
__device__ __forceinline__ float2 ldu2(const unsigned short* p, size_t i) {
    ushort2 u = *(const ushort2*)(p + i);
    float2 r; r.x = bf2f(u.x); r.y = bf2f(u.y); return r;
}

// ---- mega: LDS-hist [0,BE+BG) || xW1 GEMM || W_combo -----------------------
// hist: per-block LDS histogram (20000 counters, 80 KB) over a 6400-item
// chunk; LDS atomicAdd returns per-item rank -> posarr; counts plane dumped.
// NO global atomics. GEMM part reuses the same 80 KB LDS via union.
__global__ __launch_bounds__(256) void mega_kernel(
    const int* __restrict__ dst, const int* __restrict__ ego_flat,
    int* __restrict__ counts_e, int* __restrict__ counts_g, int* __restrict__ posarr,
    const float* __restrict__ x, const float* __restrict__ W1,
    unsigned short* __restrict__ xW1,
    const float* __restrict__ We2, const float* __restrict__ Wg2,
    const float* __restrict__ be2, float* __restrict__ Wc, float* __restrict__ bc) {
    __shared__ int4 smem4[NN / 4];          // 80 KB, shared by hist & GEMM
    const int t = threadIdx.x;
    if (blockIdx.x < BE + BG) {             // ---- LDS histogram part ----
        int* hcnt = (int*)smem4;
        const bool isE = blockIdx.x < BE;
        const int b = isE ? blockIdx.x : blockIdx.x - BE;
        for (int k = t; k < NN; k += 256) hcnt[k] = 0;
        __syncthreads();
        const int base = b * CE;
#pragma unroll 5
        for (int it = 0; it < CE / 256; ++it) {
            const int i = base + it * 256 + t;
            const int key = isE ? dst[i] : ego_flat[i];
            const int r = atomicAdd(&hcnt[key], 1);   // LDS atomic: rank
            posarr[isE ? i : NE + i] = r;
        }
        __syncthreads();
        int* cnt = isE ? (counts_e + b * NN) : (counts_g + b * NN);
        for (int k = t; k < NN; k += 256) cnt[k] = hcnt[k];
        return;
    }
    if (blockIdx.x < BE + BG + GB1) {       // ---- GEMM: xW1 = x @ W1 -> bf16
        float (*rl)[FIN] = (float(*)[FIN])smem4;
        const int r0 = (blockIdx.x - BE - BG) * 16;
        for (int idx = t; idx < 16 * FIN; idx += 256)
            rl[idx >> 7][idx & 127] = x[(size_t)(r0 + (idx >> 7)) * FIN + (idx & 127)];
        __syncthreads();
        const int j = t & 127, g = t >> 7;
        float acc[8] = {};
        for (int k = 0; k < FIN; k += 4) {
            const float w0 = W1[k * FIN + j],       w1 = W1[(k + 1) * FIN + j];
            const float w2 = W1[(k + 2) * FIN + j], w3 = W1[(k + 3) * FIN + j];
#pragma unroll
            for (int r = 0; r < 8; ++r) {
                float4 rv = *(const float4*)&rl[g * 8 + r][k];
                acc[r] += rv.x * w0 + rv.y * w1 + rv.z * w2 + rv.w * w3;
            }
        }
#pragma unroll
        for (int r = 0; r < 8; ++r)
            xW1[(size_t)(r0 + g * 8 + r) * FIN + j] = f2bf(acc[r]);
        return;
    }
    // ---- W_combo = W_ego2 @ W_gcn2 (128x64), b_combo = b_ego2 @ W_gcn2 ----
    const int wb = blockIdx.x - BE - BG - GB1;
    if (wb < 32) {
        const int row = wb * 4 + (t >> 6);
        const int j = t & 63;
        float s = 0.f;
        for (int k = 0; k < FIN; ++k) s += We2[row * FIN + k] * Wg2[k * FOUT2 + j];
        Wc[row * FOUT2 + j] = s;
    } else if (t < FOUT2) {
        float s = 0.f;
        for (int k = 0; k < FIN; ++k) s += be2[k] * Wg2[k * FOUT2 + t];
        bc[t] = s;
    }
}

// ---- scan p1 (+folded column-scan): blockprefix in counts_*, totals scanned
__global__ __launch_bounds__(256) void scan_p1_kernel(
    int* __restrict__ counts_e, int* __restrict__ counts_g,
    int* __restrict__ scantmp, int* __restrict__ bsums, float* __restrict__ dinv) {
    const int arr = (blockIdx.x >= NB) ? 1 : 0;
    const int blk = blockIdx.x - arr * NB;
    const int t = threadIdx.x;
    const int k = blk * 256 + t;
    int run = 0;
    if (k < NN) {
        if (arr == 0) {
            for (int b = 0; b < BE; ++b) {     // coalesced: fixed b plane
                int c = counts_e[b * NN + k];
                counts_e[b * NN + k] = run;    // exclusive block-prefix
                run += c;
            }
            dinv[k] = rsqrtf((float)(run + 1));  // +1 self loop
        } else {
            for (int b = 0; b < BG; ++b) {
                int c = counts_g[b * NN + k];
                counts_g[b * NN + k] = run;
                run += c;
            }
        }
    }
    __shared__ int sh[256];
    sh[t] = run;
    __syncthreads();
    for (int o = 1; o < 256; o <<= 1) {
        int u = (t >= o) ? sh[t - o] : 0;
        __syncthreads();
        sh[t] += u;
        __syncthreads();
    }
    if (k < NN) scantmp[arr * NN + k] = sh[t] - run;  // exclusive within block
    if (t == 255) bsums[arr * NB + blk] = sh[255];
}
// ---- scan p3: each block re-derives its offset from bsums in LDS -----------
__global__ __launch_bounds__(256) void scan_p3_kernel(
    const int* __restrict__ scantmp, const int* __restrict__ bsums,
    int* __restrict__ rowstart, int* __restrict__ erowstart) {
    const int arr = (blockIdx.x >= NB) ? 1 : 0;
    const int blk = blockIdx.x - arr * NB;
    const int t = threadIdx.x;
    __shared__ int sh[256];
    int v = (t < NB) ? bsums[arr * NB + t] : 0;
    sh[t] = v;
    __syncthreads();
    for (int o = 1; o < 256; o <<= 1) {
        int u = (t >= o) ? sh[t - o] : 0;
        __syncthreads();
        sh[t] += u;
        __syncthreads();
    }
    const int blkofs = (blk == 0) ? 0 : sh[blk - 1];
    const int i = blk * 256 + t;
    if (i < NN) {
        int val = scantmp[arr * NN + i] + blkofs;
        if (arr) erowstart[i] = val; else rowstart[i] = val;
    }
    if (blockIdx.x == 0 && t == 0) { rowstart[NN] = NE; erowstart[NN] = NN * KE; }
}

// ---- bucket: pure scatter via precomputed (blockprefix + rank) -------------
__global__ void bucket2_kernel(const int* __restrict__ src, const int* __restrict__ dst,
                               const int* __restrict__ ego_flat,
                               const int* __restrict__ rowstart, const int* __restrict__ erowstart,
                               const int* __restrict__ counts_e, const int* __restrict__ counts_g,
                               const int* __restrict__ posarr,
                               int* __restrict__ csr_src, int* __restrict__ yslot) {
    const int base = blockIdx.x * 2048 + threadIdx.x;
#pragma unroll
    for (int q = 0; q < 8; ++q) {
        const int i = base + q * 256;
        if (i < TOT) {
            if (i < NE) {
                const int key = dst[i];
                const int b = i / CE;
                csr_src[rowstart[key] + counts_e[b * NN + key] + posarr[i]] = src[i];
            } else {
                const int p = i - NE;
                const int key = ego_flat[p];
                const int b = p / CE;
                yslot[p] = erowstart[key] + counts_g[b * NN + key] + posarr[i];
            }
        }
    }
}

// ---- ego apply (128-wide): Y[yslot[n,i]] = ((A@A) @ xW1[ids[n]])[i] --------
__global__ __launch_bounds__(256) void ego_apply_kernel(
    const unsigned short* __restrict__ x, const int* __restrict__ ego_ids,
    const float* __restrict__ ego_adj, const int* __restrict__ yslot,
    unsigned short* __restrict__ Y) {
    __shared__ float Ar[8][KE * APAD];
    __shared__ float As[8][256];
    __shared__ int ids[8][KE];
    __shared__ int slots[8][KE];
    const int w = threadIdx.x >> 5;
    const int c = threadIdx.x & 31;
    const int n = blockIdx.x * 8 + w;
    const float* a = ego_adj + (size_t)n * 256;
#pragma unroll
    for (int e = 0; e < 8; ++e) {
        const int idx = c * 8 + e;
        Ar[w][(idx >> 4) * APAD + (idx & 15)] = a[idx];
    }
    if (c < KE) {
        ids[w][c] = ego_ids[n * KE + c];
        slots[w][c] = yslot[n * KE + c];
    }
    __syncthreads();
    {
        const int i = c >> 1;
        const int k0 = (c & 1) * 8;
        float s[8] = {};
#pragma unroll
        for (int j = 0; j < KE; ++j) {
            const float aij = Ar[w][i * APAD + j];
            const float* arow = &Ar[w][j * APAD + k0];
#pragma unroll
            for (int q = 0; q < 8; ++q) s[q] += aij * arow[q];
        }
        float4 s0 = {s[0], s[1], s[2], s[3]}, s1 = {s[4], s[5], s[6], s[7]};
        *(float4*)&As[w][i * 16 + k0]     = s0;
        *(float4*)&As[w][i * 16 + k0 + 4] = s1;
    }
    __syncthreads();
    float4 xg[KE];
#pragma unroll
    for (int k = 0; k < KE; ++k) xg[k] = ldx4(x, (size_t)ids[w][k] * FIN + 4 * c);
#pragma unroll
    for (int i = 0; i < KE; ++i) {
        float4 acc = {0.f, 0.f, 0.f, 0.f};
#pragma unroll
        for (int k = 0; k < KE; ++k) {
            const float a2 = As[w][i * 16 + k];
            acc.x += a2 * xg[k].x; acc.y += a2 * xg[k].y;
            acc.z += a2 * xg[k].z; acc.w += a2 * xg[k].w;
        }
        ushort4 o; o.x = f2bf(acc.x); o.y = f2bf(acc.y);
        o.z = f2bf(acc.z); o.w = f2bf(acc.w);
        *(ushort4*)(Y + (size_t)slots[w][i] * FIN + 4 * c) = o;
    }
}

// ---- dual1: rows = relu(ndeg*sumY + b1); msg = (rows @ Wg1)*dinv -> bf16 ----
__global__ __launch_bounds__(256) void dual1_kernel(
    const unsigned short* __restrict__ Y, const int* __restrict__ erowstart,
    const float* __restrict__ ndeg, const float* __restrict__ b1,
    const float* __restrict__ Wg1, const float* __restrict__ dinv,
    unsigned short* __restrict__ msg) {
    constexpr int ROWS = 8;
    const int r0 = blockIdx.x * ROWS;
    const int t = threadIdx.x;
    __shared__ float rows[ROWS][FIN];
    {
        const int wv = t >> 6;
        const int h  = (t >> 5) & 1;
        const int c  = t & 31;
        for (int rr = 0; rr < ROWS; rr += 4) {
            const int r = rr + wv;
            const int v = r0 + r;
            float4 acc = {0.f, 0.f, 0.f, 0.f};
            const int send = erowstart[v + 1];
            int s = erowstart[v] + h;
            for (; s + 2 < send; s += 4) {
                float4 a = ldx4(Y, (size_t)s * FIN + 4 * c);
                float4 d4 = ldx4(Y, (size_t)(s + 2) * FIN + 4 * c);
                acc.x += a.x + d4.x; acc.y += a.y + d4.y;
                acc.z += a.z + d4.z; acc.w += a.w + d4.w;
            }
            if (s < send) {
                float4 a = ldx4(Y, (size_t)s * FIN + 4 * c);
                acc.x += a.x; acc.y += a.y; acc.z += a.z; acc.w += a.w;
            }
            acc.x += __shfl_xor(acc.x, 32);
            acc.y += __shfl_xor(acc.y, 32);
            acc.z += __shfl_xor(acc.z, 32);
            acc.w += __shfl_xor(acc.w, 32);
            if (h == 0) {
                const float nd = ndeg[v];
                const float4 bb = *(const float4*)&b1[4 * c];
                float4 o;
                o.x = fmaxf(acc.x * nd + bb.x, 0.f);
                o.y = fmaxf(acc.y * nd + bb.y, 0.f);
                o.z = fmaxf(acc.z * nd + bb.z, 0.f);
                o.w = fmaxf(acc.w * nd + bb.w, 0.f);
                *(float4*)&rows[r][4 * c] = o;
            }
        }
    }
    __syncthreads();
    {
        const int j = t & 127;
        const int g = t >> 7;
        float acc[4] = {};
        for (int k = 0; k < FIN; k += 4) {
            const float w0 = Wg1[k * FIN + j],       w1 = Wg1[(k + 1) * FIN + j];
            const float w2 = Wg1[(k + 2) * FIN + j], w3 = Wg1[(k + 3) * FIN + j];
#pragma unroll
            for (int r = 0; r < 4; ++r) {
                float4 rv = *(const float4*)&rows[g * 4 + r][k];
                acc[r] += rv.x * w0 + rv.y * w1 + rv.z * w2 + rv.w * w3;
            }
        }
#pragma unroll
        for (int r = 0; r < 4; ++r) {
            const int v = r0 + g * 4 + r;
            msg[(size_t)v * FIN + j] = f2bf(acc[r] * dinv[v]);
        }
    }
}

// ------- GCN gather (F=128), half-split ushort4 -----------------------------
__global__ __launch_bounds__(256) void gcn_gather128_kernel(
    const unsigned short* __restrict__ msg, const int* __restrict__ rowstart,
    const int* __restrict__ csr_src, const float* __restrict__ dinv,
    const float* __restrict__ b, unsigned short* __restrict__ out) {
    const int tid = threadIdx.x;
    const int d = blockIdx.x * 4 + (tid >> 6);
    const int h = (tid >> 5) & 1;
    const int c = tid & 31;
    float4 acc = {0.f, 0.f, 0.f, 0.f};
    if (h == 0) acc = ldx4(msg, (size_t)d * FIN + 4 * c);  // self loop
    const int eend = rowstart[d + 1];
    int e = rowstart[d] + h;
    for (; e + 2 < eend; e += 4) {
        int s0 = csr_src[e], s1 = csr_src[e + 2];
        float4 a = ldx4(msg, (size_t)s0 * FIN + 4 * c);
        float4 d4 = ldx4(msg, (size_t)s1 * FIN + 4 * c);
        acc.x += a.x + d4.x; acc.y += a.y + d4.y;
        acc.z += a.z + d4.z; acc.w += a.w + d4.w;
    }
    if (e < eend) {
        float4 a = ldx4(msg, (size_t)csr_src[e] * FIN + 4 * c);
        acc.x += a.x; acc.y += a.y; acc.z += a.z; acc.w += a.w;
    }
    acc.x += __shfl_xor(acc.x, 32);
    acc.y += __shfl_xor(acc.y, 32);
    acc.z += __shfl_xor(acc.z, 32);
    acc.w += __shfl_xor(acc.w, 32);
    if (h == 0) {
        const float di = dinv[d];
        const float4 bb = *(const float4*)&b[4 * c];
        ushort4 o;
        o.x = f2bf(acc.x * di + bb.x); o.y = f2bf(acc.y * di + bb.y);
        o.z = f2bf(acc.z * di + bb.z); o.w = f2bf(acc.w * di + bb.w);
        *(ushort4*)(out + (size_t)d * FIN + 4 * c) = o;
    }
}

// ---- gemm2: hW2 = hA @ W_combo (128->64) -> bf16 ---------------------------
__global__ __launch_bounds__(256) void gemm2_kernel(
    const unsigned short* __restrict__ hA, const float* __restrict__ Wc,
    unsigned short* __restrict__ hW2) {
    __shared__ float rl[16][FIN];
    const int t = threadIdx.x;
    const int r0 = blockIdx.x * 16;
    for (int idx = t; idx < 16 * FIN; idx += 256)
        rl[idx >> 7][idx & 127] = bf2f(hA[(size_t)(r0 + (idx >> 7)) * FIN + (idx & 127)]);
    __syncthreads();
    const int j = t & 63, g = t >> 6;
    float acc[4] = {};
    for (int k = 0; k < FIN; k += 4) {
        const float w0 = Wc[k * FOUT2 + j],       w1 = Wc[(k + 1) * FOUT2 + j];
        const float w2 = Wc[(k + 2) * FOUT2 + j], w3 = Wc[(k + 3) * FOUT2 + j];
#pragma unroll
        for (int r = 0; r < 4; ++r) {
            float4 rv = *(const float4*)&rl[g * 4 + r][k];
            acc[r] += rv.x * w0 + rv.y * w1 + rv.z * w2 + rv.w * w3;
        }
    }
#pragma unroll
    for (int r = 0; r < 4; ++r)
        hW2[(size_t)(r0 + g * 4 + r) * FOUT2 + j] = f2bf(acc[r]);
}

// ---- ego apply (64-wide): Y2[yslot] = (A@A) @ hW2[ids] ---------------------
__global__ __launch_bounds__(256) void apply2_kernel(
    const unsigned short* __restrict__ hW2, const int* __restrict__ ego_ids,
    const float* __restrict__ ego_adj, const int* __restrict__ yslot,
    unsigned short* __restrict__ Y2) {
    __shared__ float Ar[8][KE * APAD];
    __shared__ float As[8][256];
    __shared__ int ids[8][KE];
    __shared__ int slots[8][KE];
    const int w = threadIdx.x >> 5;
    const int c = threadIdx.x & 31;
    const int n = blockIdx.x * 8 + w;
    const float* a = ego_adj + (size_t)n * 256;
#pragma unroll
    for (int e = 0; e < 8; ++e) {
        const int idx = c * 8 + e;
        Ar[w][(idx >> 4) * APAD + (idx & 15)] = a[idx];
    }
    if (c < KE) {
        ids[w][c] = ego_ids[n * KE + c];
        slots[w][c] = yslot[n * KE + c];
    }
    __syncthreads();
    {
        const int i = c >> 1;
        const int k0 = (c & 1) * 8;
        float s[8] = {};
#pragma unroll
        for (int j = 0; j < KE; ++j) {
            const float aij = Ar[w][i * APAD + j];
            const float* arow = &Ar[w][j * APAD + k0];
#pragma unroll
            for (int q = 0; q < 8; ++q) s[q] += aij * arow[q];
        }
        float4 s0 = {s[0], s[1], s[2], s[3]}, s1 = {s[4], s[5], s[6], s[7]};
        *(float4*)&As[w][i * 16 + k0]     = s0;
        *(float4*)&As[w][i * 16 + k0 + 4] = s1;
    }
    __syncthreads();
    float2 xg[KE];
#pragma unroll
    for (int k = 0; k < KE; ++k) xg[k] = ldu2(hW2, (size_t)ids[w][k] * FOUT2 + 2 * c);
#pragma unroll
    for (int i = 0; i < KE; ++i) {
        float sx = 0.f, sy = 0.f;
#pragma unroll
        for (int k = 0; k < KE; ++k) {
            const float a2 = As[w][i * 16 + k];
            sx += a2 * xg[k].x; sy += a2 * xg[k].y;
        }
        ushort2 o; o.x = f2bf(sx); o.y = f2bf(sy);
        *(ushort2*)(Y2 + (size_t)slots[w][i] * FOUT2 + 2 * c) = o;
    }
}

// ---- dual2 (matmul-free): m2 = ((ndeg*sumY2) + b_combo)*dinv -> bf16 -------
__global__ __launch_bounds__(256) void dual2_kernel(
    const unsigned short* __restrict__ Y2, const int* __restrict__ erowstart,
    const float* __restrict__ ndeg, const float* __restrict__ bc,
    const float* __restrict__ dinv, unsigned short* __restrict__ m2) {
    const int tid = threadIdx.x;
    const int d = blockIdx.x * 4 + (tid >> 6);
    const int h = (tid >> 5) & 1;
    const int c = tid & 31;
    float2 acc = {0.f, 0.f};
    const int send = erowstart[d + 1];
    int s = erowstart[d] + h;
    for (; s + 2 < send; s += 4) {
        float2 a = ldu2(Y2, (size_t)s * FOUT2 + 2 * c);
        float2 b2 = ldu2(Y2, (size_t)(s + 2) * FOUT2 + 2 * c);
        acc.x += a.x + b2.x; acc.y += a.y + b2.y;
    }
    if (s < send) {
        float2 a = ldu2(Y2, (size_t)s * FOUT2 + 2 * c);
        acc.x += a.x; acc.y += a.y;
    }
    acc.x += __shfl_xor(acc.x, 32);
    acc.y += __shfl_xor(acc.y, 32);
    if (h == 0) {
        const float nd = ndeg[d], di = dinv[d];
        const float2 bb = *(const float2*)&bc[2 * c];
        ushort2 o;
        o.x = f2bf((acc.x * nd + bb.x) * di);
        o.y = f2bf((acc.y * nd + bb.y) * di);
        *(ushort2*)(m2 + (size_t)d * FOUT2 + 2 * c) = o;
    }
}

// ------- fused GCN gather (F=64) + bias + log_softmax -> fp32 ---------------
__global__ __launch_bounds__(256) void gcn_gather_lsm_kernel(
    const unsigned short* __restrict__ msg, const int* __restrict__ rowstart,
    const int* __restrict__ csr_src, const float* __restrict__ dinv,
    const float* __restrict__ b, float* __restrict__ out) {
    const int tid = threadIdx.x;
    const int d = blockIdx.x * 4 + (tid >> 6);
    const int t = tid & 63;
    float s = bf2f(msg[(size_t)d * FOUT2 + t]);  // self loop
    int e = rowstart[d];
    const int eend = rowstart[d + 1];
    for (; e + 4 <= eend; e += 4) {
        int s0 = csr_src[e], s1 = csr_src[e + 1], s2 = csr_src[e + 2], s3 = csr_src[e + 3];
        s += bf2f(msg[(size_t)s0 * FOUT2 + t]) + bf2f(msg[(size_t)s1 * FOUT2 + t])
           + bf2f(msg[(size_t)s2 * FOUT2 + t]) + bf2f(msg[(size_t)s3 * FOUT2 + t]);
    }
    for (; e < eend; ++e) s += bf2f(msg[(size_t)csr_src[e] * FOUT2 + t]);
    const float xv = s * dinv[d] + b[t];
    float m = xv;
#pragma unroll
    for (int o = 32; o > 0; o >>= 1) m = fmaxf(m, __shfl_xor(m, o));
    float ex = __expf(xv - m);
    float sm = ex;
#pragma unroll
    for (int o = 32; o > 0; o >>= 1) sm += __shfl_xor(sm, o);
    out[(size_t)d * FOUT2 + t] = xv - m - __logf(sm);
}

extern "C" void kernel_launch(void* const* d_in, const int* in_sizes, int n_in,
                              void* d_out, int out_size, void* d_ws, size_t ws_size,
                              hipStream_t stream) {
    (void)in_sizes; (void)n_in; (void)out_size; (void)ws_size;
    const float* x      = (const float*)d_in[0];
    const int*   eidx   = (const int*)d_in[1];
    const int*   egoids = (const int*)d_in[2];
    const float* egoadj = (const float*)d_in[3];
    const float* ndeg   = (const float*)d_in[4];
    const float* W_ego1 = (const float*)d_in[5];
    const float* b_ego1 = (const float*)d_in[6];
    const float* W_gcn1 = (const float*)d_in[7];
    const float* b_gcn1 = (const float*)d_in[8];
    const float* W_ego2 = (const float*)d_in[9];
    const float* b_ego2 = (const float*)d_in[10];
    const float* W_gcn2 = (const float*)d_in[11];
    const float* b_gcn2 = (const float*)d_in[12];
    const int* src = eidx;
    const int* dst = eidx + NE;

    // ---- workspace layout (~122 MB) ----
    int* ip = (int*)d_ws;
    int* counts_e  = ip;                    // BE*NN (written by mega)
    int* counts_g  = counts_e + BE * NN;    // BG*NN
    int* rowstart  = counts_g + BG * NN;    // NN+1 (+pad)
    int* erowstart = rowstart + NN + 8;     // NN+1 (+pad)
    int* csr_src   = erowstart + NN + 8;    // NE
    int* yslot     = csr_src + NE;          // NN*KE
    int* scantmp   = yslot + NN * KE;       // 2*NN
    int* bsums     = scantmp + 2 * NN;      // 2*NB (+pad)
    int* posarr    = bsums + 256;           // TOT
    float* dinv = (float*)(posarr + TOT);               // NN
    float* Wc   = dinv + NN;                            // 128*64 fp32
    float* bc   = Wc + FIN * FOUT2;                     // 64 (+pad)
    unsigned short* xW1 = (unsigned short*)(bc + 64);    // NN*128 bf16
    unsigned short* mA  = xW1 + (size_t)NN * FIN;        // NN*128 bf16 msgs L1
    unsigned short* hA  = mA + (size_t)NN * FIN;         // NN*128 bf16 hidden
    unsigned short* hW2 = hA + (size_t)NN * FIN;         // NN*64  bf16
    unsigned short* m2  = hW2 + (size_t)NN * FOUT2;      // NN*64  bf16 msgs L2
    unsigned short* Y   = m2 + (size_t)NN * FOUT2;       // NN*KE*128 bf16 (CSR order)

    // ---- CSR build (LDS hist, no global atomics) || xW1 GEMM || W_combo ----
    mega_kernel<<<BE + BG + GB1 + 33, 256, 0, stream>>>(dst, egoids,
                                                        counts_e, counts_g, posarr,
                                                        x, W_ego1, xW1,
                                                        W_ego2, W_gcn2, b_ego2, Wc, bc);
    scan_p1_kernel<<<2 * NB, 256, 0, stream>>>(counts_e, counts_g, scantmp, bsums, dinv);
    scan_p3_kernel<<<2 * NB, 256, 0, stream>>>(scantmp, bsums, rowstart, erowstart);
    bucket2_kernel<<<HB, 256, 0, stream>>>(src, dst, egoids, rowstart, erowstart,
                                           counts_e, counts_g, posarr, csr_src, yslot);

    // ---- layer 1 ----
    ego_apply_kernel<<<NN / 8, 256, 0, stream>>>(xW1, egoids, egoadj, yslot, Y);
    dual1_kernel<<<NN / 8, 256, 0, stream>>>(Y, erowstart, ndeg, b_ego1, W_gcn1, dinv, mA);
    gcn_gather128_kernel<<<NN / 4, 256, 0, stream>>>(mA, rowstart, csr_src, dinv, b_gcn1, hA);

    // ---- layer 2 (weights pre-combined; ego runs on 64-wide hW2) ----
    gemm2_kernel<<<GB1, 256, 0, stream>>>(hA, Wc, hW2);
    apply2_kernel<<<NN / 8, 256, 0, stream>>>(hW2, egoids, egoadj, yslot, Y);
    dual2_kernel<<<NN / 4, 256, 0, stream>>>(Y, erowstart, ndeg, bc, dinv, m2);
    gcn_gather_lsm_kernel<<<NN / 4, 256, 0, stream>>>(m2, rowstart, csr_src, dinv, b_gcn2, (float*)d_out);
}